// Round 7
// baseline (657.361 us; speedup 1.0000x reference)
//
#include <hip/hip_runtime.h>

// DecoderRNN v7: 3-layer GRU, B=32768, H=100, 21 steps, VOCAB=20.
// = v6 (8 waves x 128 rows, static 128KB LDS, 2 barriers/phase, exp2-form
// activations) + REGISTER-PINNED per-phase weights.
// v6 PMC showed VGPR=124: compiler rematerialized the 24 weight frag8 loads
// inside every grp iter -> 21.7 GB of L2 reads = 33.7 TB/s = L2 ceiling.
// Empty inline-asm "+v" on each fragment makes the loaded values opaque so
// the compiler must keep them resident across all 8 grps (live set ~170 regs,
// fits the 256 cap implied by __launch_bounds__(512,2)).

#define NTHR 512
#define NBLK 256
#define ROWS_PB 128

// wp (u16) offsets
#define OFF_PROJ 0                 // [112][128]
#define OFF_IH0  14336             // each [336][128]: row g*112+nn, col 100 = bias
#define OFF_HH0  57344
#define OFF_IH1  100352
#define OFF_HH1  143360
#define OFF_IH2  186368
#define OFF_HH2  229376
#define OFF_OUT  272384            // [32][128], col 100 = b_out (rows 20..31 zero)
#define WP_TOTAL 276480

// LDS (u16): 4 buffers [128][128], 16B-chunk XOR swizzle
#define X0_OFF   0
#define H0_OFF   16384
#define H1_OFF   32768
#define H2_OFF   49152
#define SMEM_U16 65536             // 131072 B static

using frag8 = __attribute__((ext_vector_type(8))) short;
using frag4 = __attribute__((ext_vector_type(4))) short;
using f32x4 = __attribute__((ext_vector_type(4))) float;

struct G4 { frag8 a, b, c, d; };

__device__ __forceinline__ unsigned short f2b(float f) {
    union { float f; unsigned u; } v; v.f = f;
    unsigned r = v.u + 0x7FFF + ((v.u >> 16) & 1);   // RNE
    return (unsigned short)(r >> 16);
}
__device__ __forceinline__ float b2f(unsigned short b) {
    union { unsigned u; float f; } v; v.u = ((unsigned)b) << 16; return v.f;
}

__device__ __forceinline__ f32x4 mfma32(frag8 a, frag8 b, f32x4 c) {
    return __builtin_amdgcn_mfma_f32_16x16x32_bf16(a, b, c, 0, 0, 0);
}
__device__ __forceinline__ f32x4 dot4(const G4& w, const G4& s, f32x4 acc) {
    acc = mfma32(w.a, s.a, acc); acc = mfma32(w.b, s.b, acc);
    acc = mfma32(w.c, s.c, acc); return mfma32(w.d, s.d, acc);
}
// make the loaded fragment opaque: compiler cannot rematerialize it from
// memory, so it stays in VGPRs for its whole live range.
__device__ __forceinline__ void pin(G4& w) {
    asm volatile("" : "+v"(w.a), "+v"(w.b), "+v"(w.c), "+v"(w.d));
}

// ---------------- weight prep: f32 -> bf16, padded, bias col 100, prescaled ----
__global__ void prep_kernel(const float* __restrict__ w_proj,
    const float* __restrict__ wih0, const float* __restrict__ bih0,
    const float* __restrict__ whh0, const float* __restrict__ bhh0,
    const float* __restrict__ wih1, const float* __restrict__ bih1,
    const float* __restrict__ whh1, const float* __restrict__ bhh1,
    const float* __restrict__ wih2, const float* __restrict__ bih2,
    const float* __restrict__ whh2, const float* __restrict__ bhh2,
    const float* __restrict__ w_out, const float* __restrict__ b_out,
    unsigned short* __restrict__ dst)
{
    const float LOG2E  = 1.4426950408889634f;
    const float LOG2E2 = 2.8853900817779268f;
    int idx = blockIdx.x * 256 + threadIdx.x;
    if (idx >= WP_TOTAL) return;
    float v = 0.f;
    if (idx < OFF_IH0) {
        int n = idx >> 7, k = idx & 127;
        if (n < 100) v = w_proj[n * 128 + k];
    } else if (idx < OFF_OUT) {
        int r = idx - OFF_IH0;
        int mi = r / 43008;
        int e  = r - mi * 43008;
        int n = e >> 7, k = e & 127;
        int g = n / 112, nn = n - g * 112;
        if (nn < 100) {
            const float* W; const float* Bv;
            switch (mi) {
                case 0: W = wih0; Bv = bih0; break;
                case 1: W = whh0; Bv = bhh0; break;
                case 2: W = wih1; Bv = bih1; break;
                case 3: W = whh1; Bv = bhh1; break;
                case 4: W = wih2; Bv = bih2; break;
                default: W = whh2; Bv = bhh2; break;
            }
            if (k < 100) v = W[(g * 100 + nn) * 100 + k];
            else if (k == 100) v = Bv[g * 100 + nn];
            v *= (g == 2) ? LOG2E2 : LOG2E;       // exp2-form activations
        }
    } else {
        int e = idx - OFF_OUT;
        int n = e >> 7, k = e & 127;
        if (n < 20) {
            if (k < 100) v = w_out[n * 100 + k];
            else if (k == 100) v = b_out[n];
        }
    }
    dst[idx] = f2b(v);
}

// ---------------- LDS helpers (swizzled) ----------------
// logical u16 col cu of row r stored at 8-u16 chunk (cu>>3) ^ (r&7)
__device__ __forceinline__ int hsw(int buf, int grp, int r, int cu) {
    int row = grp * 16 + r;
    return buf + row * 128 + ((((cu >> 3) ^ (row & 7)) << 3) | (cu & 7));
}
__device__ __forceinline__ G4 ldSG4(const unsigned short* sm, int buf, int grp, int c16, int g4) {
    const unsigned short* p = sm + buf + (grp * 16 + c16) * 128;
    int x = c16 & 7;
    G4 s;
    s.a = *(const frag8*)(p + ((g4 ^ x) << 3));
    s.b = *(const frag8*)(p + (((4 + g4) ^ x) << 3));
    s.c = *(const frag8*)(p + (((8 + g4) ^ x) << 3));
    s.d = *(const frag8*)(p + (((12 + g4) ^ x) << 3));
    return s;
}

// ---------------- weight loader ----------------
__device__ __forceinline__ G4 ldWG4(const unsigned short* __restrict__ m, int g, int ro, int g4) {
    const unsigned short* p = m + (size_t)(g * 112 + ro) * 128 + g4 * 8;
    G4 w;
    w.a = *(const frag8*)p;        w.b = *(const frag8*)(p + 32);
    w.c = *(const frag8*)(p + 64); w.d = *(const frag8*)(p + 96);
    return w;
}

__device__ __forceinline__ void logits_one(const unsigned short* sm,
        const G4& O0, const G4& O1, int grp, int lt,
        float* __restrict__ out, int rbase, int c16, int g4) {
    G4 L = ldSG4(sm, H2_OFF, grp, c16, g4);
    f32x4 a0 = {0.f, 0.f, 0.f, 0.f}, a1 = a0;
    a0 = dot4(O0, L, a0);
    a1 = dot4(O1, L, a1);
    float* po = out + (size_t)(rbase + grp * 16 + c16) * 420 + lt * 20;
    *(f32x4*)(po + g4 * 4) = a0;           // vocab 4*g4 .. +4
    if (g4 == 0) *(f32x4*)(po + 16) = a1;  // vocab 16..19
}

// ---------------- one GRU layer phase (2 barriers) ----------------
template<bool PH0>
__device__ __forceinline__ void gru_phase(unsigned short* sm, int HS, int HD,
    const unsigned short* __restrict__ wih, const unsigned short* __restrict__ whh,
    const G4* O, int lt, float* __restrict__ out, int rbase,
    bool owner, bool vald, int c16, int g4, int ro, int nbase)
{
    G4 Wi[3], Wh[3];
    if (owner) {
#pragma unroll
        for (int g = 0; g < 3; ++g) { Wi[g] = ldWG4(wih, g, ro, g4); Wh[g] = ldWG4(whh, g, ro, g4); }
        pin(Wi[0]); pin(Wi[1]); pin(Wi[2]);
        pin(Wh[0]); pin(Wh[1]); pin(Wh[2]);
    }
    __syncthreads();                              // B0: prev-phase writes visible
    frag4 hn[8];
#pragma unroll
    for (int grp = 0; grp < 8; ++grp) {
        if (owner) {
            G4 S = ldSG4(sm, HS, grp, c16, g4);
            G4 D = ldSG4(sm, HD, grp, c16, g4);
            f32x4 ar = {0.f, 0.f, 0.f, 0.f}, az = ar, anx = ar, anh = ar;
            ar  = dot4(Wi[0], S, ar);   ar  = dot4(Wh[0], D, ar);
            az  = dot4(Wi[1], S, az);   az  = dot4(Wh[1], D, az);
            anx = dot4(Wi[2], S, anx);  anh = dot4(Wh[2], D, anh);
            frag4 hold = *(const frag4*)(sm + hsw(HD, grp, c16, nbase));
#pragma unroll
            for (int j = 0; j < 4; ++j) {
                float r  = __builtin_amdgcn_rcpf(1.f + __builtin_amdgcn_exp2f(-ar[j]));
                float z  = __builtin_amdgcn_rcpf(1.f + __builtin_amdgcn_exp2f(-az[j]));
                float y  = anx[j] + r * anh[j];
                float nn = 1.f - 2.f * __builtin_amdgcn_rcpf(1.f + __builtin_amdgcn_exp2f(y));
                float ho = b2f((unsigned short)hold[j]);
                hn[grp][j] = (short)f2b(nn + z * (ho - nn));
            }
        } else if (PH0 && lt >= 0) {
            logits_one(sm, O[0], O[1], grp, lt, out, rbase, c16, g4);
        }
    }
    __syncthreads();                              // B1: all reads of old HD done
    if (owner && vald) {
#pragma unroll
        for (int grp = 0; grp < 8; ++grp)
            *(frag4*)(sm + hsw(HD, grp, c16, nbase)) = hn[grp];
    }
}

// ---------------- main kernel ----------------
__global__ void __launch_bounds__(NTHR, 2) rnn_kernel(
    const float* __restrict__ enc,
    const float* __restrict__ b_proj,
    const unsigned short* __restrict__ wp,
    float* __restrict__ out)
{
    __shared__ unsigned short sm[SMEM_U16];       // 128 KB static -> 1 block/CU visible
    const int tid  = threadIdx.x;
    const int lane = tid & 63;
    const int wid  = tid >> 6;
    const int c16  = lane & 15;
    const int g4   = lane >> 4;
    const int rbase = blockIdx.x * ROWS_PB;
    const bool owner = (wid < 7);
    const int tw    = owner ? wid : 0;
    const int ro    = tw * 16 + c16;
    const int nbase = tw * 16 + g4 * 4;
    const bool vald = owner && (nbase < 100);

    // ---- init LDS: zeros, logical col 100 = 1.0 (bias) ----
    for (int i = tid; i < SMEM_U16; i += NTHR) {
        int r  = (i >> 7) & 127;
        int cu = i & 127;
        int lcol = ((((cu >> 3) ^ (r & 7)) << 3) | (cu & 7));
        sm[i] = (lcol == 100) ? (unsigned short)0x3F80 : (unsigned short)0;
    }

    // ---- wave 7: persistent w_out fragments (pinned) ----
    G4 O[2];
    if (!owner) {
        O[0] = ldWG4(wp + OFF_OUT, 0, c16, g4);
        O[1] = ldWG4(wp + OFF_OUT, 0, 16 + c16, g4);
        pin(O[0]); pin(O[1]);
    }
    __syncthreads();

    // ---- prologue: x0 = enc @ w_proj^T + b_proj -> X0 (K=128 exact) ----
    if (owner) {
        G4 P = ldWG4(wp + OFF_PROJ, 0, ro, g4);
        f32x4 bp = {0.f, 0.f, 0.f, 0.f};
        if (vald) bp = *(const f32x4*)(b_proj + nbase);
#pragma unroll 1
        for (int grp = 0; grp < 8; ++grp) {
            const float* ep = enc + (size_t)(rbase + grp * 16 + c16) * 128 + g4 * 8;
            G4 E;
            {
                frag8 e0, e1, e2, e3;
#pragma unroll
                for (int j = 0; j < 8; ++j) {
                    e0[j] = (short)f2b(ep[j]);      e1[j] = (short)f2b(ep[32 + j]);
                    e2[j] = (short)f2b(ep[64 + j]); e3[j] = (short)f2b(ep[96 + j]);
                }
                E.a = e0; E.b = e1; E.c = e2; E.d = e3;
            }
            f32x4 acc = dot4(P, E, bp);
            if (vald) {
                frag4 xv;
#pragma unroll
                for (int j = 0; j < 4; ++j) xv[j] = (short)f2b(acc[j]);
                *(frag4*)(sm + hsw(X0_OFF, grp, c16, nbase)) = xv;
            }
        }
    }
    // (first phase's B0 provides the needed sync)

    // ---- time loop: three phases; wave 7 logits(t-1) during phase 0 ----
#pragma unroll 1
    for (int t = 0; t < 21; ++t) {
        gru_phase<true >(sm, X0_OFF, H0_OFF, wp + OFF_IH0, wp + OFF_HH0,
                         O, t - 1, out, rbase, owner, vald, c16, g4, ro, nbase);
        gru_phase<false>(sm, H0_OFF, H1_OFF, wp + OFF_IH1, wp + OFF_HH1,
                         O, -1, out, rbase, owner, vald, c16, g4, ro, nbase);
        gru_phase<false>(sm, H1_OFF, H2_OFF, wp + OFF_IH2, wp + OFF_HH2,
                         O, -1, out, rbase, owner, vald, c16, g4, ro, nbase);
    }

    // ---- tail: logits for t=20 (wave 7) ----
    __syncthreads();
    if (!owner) {
#pragma unroll 1
        for (int grp = 0; grp < 8; ++grp)
            logits_one(sm, O[0], O[1], grp, 20, out, rbase, c16, g4);
    }
}

extern "C" void kernel_launch(void* const* d_in, const int* in_sizes, int n_in,
                              void* d_out, int out_size, void* d_ws, size_t ws_size,
                              hipStream_t stream) {
    const float* enc    = (const float*)d_in[0];
    const float* w_proj = (const float*)d_in[1];
    const float* b_proj = (const float*)d_in[2];
    const float* wih0   = (const float*)d_in[3];
    const float* whh0   = (const float*)d_in[4];
    const float* bih0   = (const float*)d_in[5];
    const float* bhh0   = (const float*)d_in[6];
    const float* wih1   = (const float*)d_in[7];
    const float* whh1   = (const float*)d_in[8];
    const float* bih1   = (const float*)d_in[9];
    const float* bhh1   = (const float*)d_in[10];
    const float* wih2   = (const float*)d_in[11];
    const float* whh2   = (const float*)d_in[12];
    const float* bih2   = (const float*)d_in[13];
    const float* bhh2   = (const float*)d_in[14];
    const float* w_out  = (const float*)d_in[15];
    const float* b_out  = (const float*)d_in[16];
    unsigned short* wpd = (unsigned short*)d_ws;   // 552,960 B used
    float* out          = (float*)d_out;

    prep_kernel<<<(WP_TOTAL + 255) / 256, 256, 0, stream>>>(
        w_proj, wih0, bih0, whh0, bhh0, wih1, bih1, whh1, bhh1,
        wih2, bih2, whh2, bhh2, w_out, b_out, wpd);

    rnn_kernel<<<NBLK, NTHR, 0, stream>>>(enc, b_proj, wpd, out);
}

// Round 9
// 524.667 us; speedup vs baseline: 1.2529x; 1.2529x over previous
//
#include <hip/hip_runtime.h>

// DecoderRNN v9: 3-layer GRU, B=32768, H=100, 21 steps, VOCAB=20.
// = v6 (8 waves x 128 rows, static 128KB LDS, 2 barriers/phase, exp2-form
// activations) + GATE-SPLIT passes to kill the L2 remat wall.
// v6 PMC: compiler caps arch VGPRs at ~124 -> 24 resident weight frags don't
// fit -> per-grp remat = 22.2 GB L2 reads = 34.5 TB/s = L2 ceiling = 643us.
// v9: per pass only ONE gate's weights live (2 G4 = 32 regs, pinned via
// empty "+v" asm -> no remat), swept over all 8 grps; r,z parked as packed
// bf16 (32 regs). Peak live ~120 <= 124 budget. Weights hit L2 once/phase:
// 2.7 GB total. Builtin MFMA ONLY (v8's asm MFMA corrupted silently).

#define NTHR 512
#define NBLK 256
#define ROWS_PB 128

// wp (u16) offsets
#define OFF_PROJ 0                 // [112][128]
#define OFF_IH0  14336             // each [336][128]: row g*112+nn, col 100 = bias
#define OFF_HH0  57344
#define OFF_IH1  100352
#define OFF_HH1  143360
#define OFF_IH2  186368
#define OFF_HH2  229376
#define OFF_OUT  272384            // [32][128], col 100 = b_out (rows 20..31 zero)
#define WP_TOTAL 276480

// LDS (u16): 4 buffers [128][128], 16B-chunk XOR swizzle
#define X0_OFF   0
#define H0_OFF   16384
#define H1_OFF   32768
#define H2_OFF   49152
#define SMEM_U16 65536             // 131072 B static

using frag8 = __attribute__((ext_vector_type(8))) short;
using frag4 = __attribute__((ext_vector_type(4))) short;
using f32x4 = __attribute__((ext_vector_type(4))) float;

struct G4 { frag8 a, b, c, d; };

__device__ __forceinline__ unsigned short f2b(float f) {
    union { float f; unsigned u; } v; v.f = f;
    unsigned r = v.u + 0x7FFF + ((v.u >> 16) & 1);   // RNE
    return (unsigned short)(r >> 16);
}
__device__ __forceinline__ float b2f(unsigned short b) {
    union { unsigned u; float f; } v; v.u = ((unsigned)b) << 16; return v.f;
}

__device__ __forceinline__ f32x4 mfma32(frag8 a, frag8 b, f32x4 c) {
    return __builtin_amdgcn_mfma_f32_16x16x32_bf16(a, b, c, 0, 0, 0);
}
__device__ __forceinline__ f32x4 dot4(const G4& w, const G4& s, f32x4 acc) {
    acc = mfma32(w.a, s.a, acc); acc = mfma32(w.b, s.b, acc);
    acc = mfma32(w.c, s.c, acc); return mfma32(w.d, s.d, acc);
}
// keep a loaded fragment opaque -> compiler cannot rematerialize its load
__device__ __forceinline__ void pin(G4& w) {
    asm volatile("" : "+v"(w.a), "+v"(w.b), "+v"(w.c), "+v"(w.d));
}

// ---------------- weight prep: f32 -> bf16, padded, bias col 100, prescaled ----
__global__ void prep_kernel(const float* __restrict__ w_proj,
    const float* __restrict__ wih0, const float* __restrict__ bih0,
    const float* __restrict__ whh0, const float* __restrict__ bhh0,
    const float* __restrict__ wih1, const float* __restrict__ bih1,
    const float* __restrict__ whh1, const float* __restrict__ bhh1,
    const float* __restrict__ wih2, const float* __restrict__ bih2,
    const float* __restrict__ whh2, const float* __restrict__ bhh2,
    const float* __restrict__ w_out, const float* __restrict__ b_out,
    unsigned short* __restrict__ dst)
{
    const float LOG2E  = 1.4426950408889634f;
    const float LOG2E2 = 2.8853900817779268f;
    int idx = blockIdx.x * 256 + threadIdx.x;
    if (idx >= WP_TOTAL) return;
    float v = 0.f;
    if (idx < OFF_IH0) {
        int n = idx >> 7, k = idx & 127;
        if (n < 100) v = w_proj[n * 128 + k];
    } else if (idx < OFF_OUT) {
        int r = idx - OFF_IH0;
        int mi = r / 43008;
        int e  = r - mi * 43008;
        int n = e >> 7, k = e & 127;
        int g = n / 112, nn = n - g * 112;
        if (nn < 100) {
            const float* W; const float* Bv;
            switch (mi) {
                case 0: W = wih0; Bv = bih0; break;
                case 1: W = whh0; Bv = bhh0; break;
                case 2: W = wih1; Bv = bih1; break;
                case 3: W = whh1; Bv = bhh1; break;
                case 4: W = wih2; Bv = bih2; break;
                default: W = whh2; Bv = bhh2; break;
            }
            if (k < 100) v = W[(g * 100 + nn) * 100 + k];
            else if (k == 100) v = Bv[g * 100 + nn];
            v *= (g == 2) ? LOG2E2 : LOG2E;       // exp2-form activations
        }
    } else {
        int e = idx - OFF_OUT;
        int n = e >> 7, k = e & 127;
        if (n < 20) {
            if (k < 100) v = w_out[n * 100 + k];
            else if (k == 100) v = b_out[n];
        }
    }
    dst[idx] = f2b(v);
}

// ---------------- LDS helpers (swizzled) ----------------
// logical u16 col cu of row r stored at 8-u16 chunk (cu>>3) ^ (r&7)
__device__ __forceinline__ int hsw(int buf, int grp, int r, int cu) {
    int row = grp * 16 + r;
    return buf + row * 128 + ((((cu >> 3) ^ (row & 7)) << 3) | (cu & 7));
}
__device__ __forceinline__ G4 ldSG4(const unsigned short* sm, int buf, int grp, int c16, int g4) {
    const unsigned short* p = sm + buf + (grp * 16 + c16) * 128;
    int x = c16 & 7;
    G4 s;
    s.a = *(const frag8*)(p + ((g4 ^ x) << 3));
    s.b = *(const frag8*)(p + (((4 + g4) ^ x) << 3));
    s.c = *(const frag8*)(p + (((8 + g4) ^ x) << 3));
    s.d = *(const frag8*)(p + (((12 + g4) ^ x) << 3));
    return s;
}

// ---------------- weight loader ----------------
__device__ __forceinline__ G4 ldWG4(const unsigned short* __restrict__ m, int g, int ro, int g4) {
    const unsigned short* p = m + (size_t)(g * 112 + ro) * 128 + g4 * 8;
    G4 w;
    w.a = *(const frag8*)p;        w.b = *(const frag8*)(p + 32);
    w.c = *(const frag8*)(p + 64); w.d = *(const frag8*)(p + 96);
    return w;
}

__device__ __forceinline__ void logits_one(const unsigned short* sm,
        const G4& O0, const G4& O1, int grp, int lt,
        float* __restrict__ out, int rbase, int c16, int g4) {
    G4 L = ldSG4(sm, H2_OFF, grp, c16, g4);
    f32x4 a0 = {0.f, 0.f, 0.f, 0.f}, a1 = a0;
    a0 = dot4(O0, L, a0);
    a1 = dot4(O1, L, a1);
    float* po = out + (size_t)(rbase + grp * 16 + c16) * 420 + lt * 20;
    *(f32x4*)(po + g4 * 4) = a0;           // vocab 4*g4 .. +4
    if (g4 == 0) *(f32x4*)(po + 16) = a1;  // vocab 16..19
}

// ---------------- one GRU layer phase: gate-split, 2 barriers ----------------
template<bool PH0>
__device__ __forceinline__ void gru_phase(unsigned short* sm, int HS, int HD,
    const unsigned short* __restrict__ wih, const unsigned short* __restrict__ whh,
    const G4* O, int lt, float* __restrict__ out, int rbase,
    bool owner, bool vald, int c16, int g4, int ro, int nbase)
{
    __syncthreads();                              // B0: prev-phase writes visible
    frag4 rp[8], zp[8], hn[8];
    if (owner) {
        // ---- pass 1: gate r ----
        G4 Wi = ldWG4(wih, 0, ro, g4), Wh = ldWG4(whh, 0, ro, g4);
        pin(Wi); pin(Wh);
#pragma unroll
        for (int grp = 0; grp < 8; ++grp) {
            G4 S = ldSG4(sm, HS, grp, c16, g4);
            G4 D = ldSG4(sm, HD, grp, c16, g4);
            f32x4 a = {0.f, 0.f, 0.f, 0.f};
            a = dot4(Wi, S, a); a = dot4(Wh, D, a);
#pragma unroll
            for (int j = 0; j < 4; ++j)
                rp[grp][j] = (short)f2b(__builtin_amdgcn_rcpf(1.f + __builtin_amdgcn_exp2f(-a[j])));
        }
        // ---- pass 2: gate z ----
        Wi = ldWG4(wih, 1, ro, g4); Wh = ldWG4(whh, 1, ro, g4);
        pin(Wi); pin(Wh);
#pragma unroll
        for (int grp = 0; grp < 8; ++grp) {
            G4 S = ldSG4(sm, HS, grp, c16, g4);
            G4 D = ldSG4(sm, HD, grp, c16, g4);
            f32x4 a = {0.f, 0.f, 0.f, 0.f};
            a = dot4(Wi, S, a); a = dot4(Wh, D, a);
#pragma unroll
            for (int j = 0; j < 4; ++j)
                zp[grp][j] = (short)f2b(__builtin_amdgcn_rcpf(1.f + __builtin_amdgcn_exp2f(-a[j])));
        }
        // ---- pass 3: gate n + combine ----
        Wi = ldWG4(wih, 2, ro, g4); Wh = ldWG4(whh, 2, ro, g4);
        pin(Wi); pin(Wh);
#pragma unroll
        for (int grp = 0; grp < 8; ++grp) {
            G4 S = ldSG4(sm, HS, grp, c16, g4);
            G4 D = ldSG4(sm, HD, grp, c16, g4);
            f32x4 ax = {0.f, 0.f, 0.f, 0.f}, ah = ax;
            ax = dot4(Wi, S, ax); ah = dot4(Wh, D, ah);
            frag4 hold = *(const frag4*)(sm + hsw(HD, grp, c16, nbase));
#pragma unroll
            for (int j = 0; j < 4; ++j) {
                float r  = b2f((unsigned short)rp[grp][j]);
                float z  = b2f((unsigned short)zp[grp][j]);
                float y  = ax[j] + r * ah[j];
                float nn = 1.f - 2.f * __builtin_amdgcn_rcpf(1.f + __builtin_amdgcn_exp2f(y));
                float ho = b2f((unsigned short)hold[j]);
                hn[grp][j] = (short)f2b(nn + z * (ho - nn));
            }
        }
    } else if (PH0 && lt >= 0) {
#pragma unroll 1
        for (int grp = 0; grp < 8; ++grp)
            logits_one(sm, O[0], O[1], grp, lt, out, rbase, c16, g4);
    }
    __syncthreads();                              // B1: all reads of old HD done
    if (owner && vald) {
#pragma unroll
        for (int grp = 0; grp < 8; ++grp)
            *(frag4*)(sm + hsw(HD, grp, c16, nbase)) = hn[grp];
    }
}

// ---------------- main kernel ----------------
__global__ void __launch_bounds__(NTHR, 2) rnn_kernel(
    const float* __restrict__ enc,
    const float* __restrict__ b_proj,
    const unsigned short* __restrict__ wp,
    float* __restrict__ out)
{
    __shared__ unsigned short sm[SMEM_U16];       // 128 KB static
    const int tid  = threadIdx.x;
    const int lane = tid & 63;
    const int wid  = tid >> 6;
    const int c16  = lane & 15;
    const int g4   = lane >> 4;
    const int rbase = blockIdx.x * ROWS_PB;
    const bool owner = (wid < 7);
    const int tw    = owner ? wid : 0;
    const int ro    = tw * 16 + c16;
    const int nbase = tw * 16 + g4 * 4;
    const bool vald = owner && (nbase < 100);

    // ---- init LDS: zeros, logical col 100 = 1.0 (bias) ----
    for (int i = tid; i < SMEM_U16; i += NTHR) {
        int r  = (i >> 7) & 127;
        int cu = i & 127;
        int lcol = ((((cu >> 3) ^ (r & 7)) << 3) | (cu & 7));
        sm[i] = (lcol == 100) ? (unsigned short)0x3F80 : (unsigned short)0;
    }

    // ---- wave 7: persistent w_out fragments ----
    G4 O[2];
    if (!owner) {
        O[0] = ldWG4(wp + OFF_OUT, 0, c16, g4);
        O[1] = ldWG4(wp + OFF_OUT, 0, 16 + c16, g4);
        pin(O[0]); pin(O[1]);
    }
    __syncthreads();

    // ---- prologue: x0 = enc @ w_proj^T + b_proj -> X0 (K=128 exact) ----
    if (owner) {
        G4 P = ldWG4(wp + OFF_PROJ, 0, ro, g4);
        f32x4 bp = {0.f, 0.f, 0.f, 0.f};
        if (vald) bp = *(const f32x4*)(b_proj + nbase);
#pragma unroll 1
        for (int grp = 0; grp < 8; ++grp) {
            const float* ep = enc + (size_t)(rbase + grp * 16 + c16) * 128 + g4 * 8;
            G4 E;
            {
                frag8 e0, e1, e2, e3;
#pragma unroll
                for (int j = 0; j < 8; ++j) {
                    e0[j] = (short)f2b(ep[j]);      e1[j] = (short)f2b(ep[32 + j]);
                    e2[j] = (short)f2b(ep[64 + j]); e3[j] = (short)f2b(ep[96 + j]);
                }
                E.a = e0; E.b = e1; E.c = e2; E.d = e3;
            }
            f32x4 acc = dot4(P, E, bp);
            if (vald) {
                frag4 xv;
#pragma unroll
                for (int j = 0; j < 4; ++j) xv[j] = (short)f2b(acc[j]);
                *(frag4*)(sm + hsw(X0_OFF, grp, c16, nbase)) = xv;
            }
        }
    }
    // (first phase's B0 provides the needed sync)

    // ---- time loop: three phases; wave 7 logits(t-1) during phase 0 ----
#pragma unroll 1
    for (int t = 0; t < 21; ++t) {
        gru_phase<true >(sm, X0_OFF, H0_OFF, wp + OFF_IH0, wp + OFF_HH0,
                         O, t - 1, out, rbase, owner, vald, c16, g4, ro, nbase);
        gru_phase<false>(sm, H0_OFF, H1_OFF, wp + OFF_IH1, wp + OFF_HH1,
                         O, -1, out, rbase, owner, vald, c16, g4, ro, nbase);
        gru_phase<false>(sm, H1_OFF, H2_OFF, wp + OFF_IH2, wp + OFF_HH2,
                         O, -1, out, rbase, owner, vald, c16, g4, ro, nbase);
    }

    // ---- tail: logits for t=20 (wave 7) ----
    __syncthreads();
    if (!owner) {
#pragma unroll 1
        for (int grp = 0; grp < 8; ++grp)
            logits_one(sm, O[0], O[1], grp, 20, out, rbase, c16, g4);
    }
}

extern "C" void kernel_launch(void* const* d_in, const int* in_sizes, int n_in,
                              void* d_out, int out_size, void* d_ws, size_t ws_size,
                              hipStream_t stream) {
    const float* enc    = (const float*)d_in[0];
    const float* w_proj = (const float*)d_in[1];
    const float* b_proj = (const float*)d_in[2];
    const float* wih0   = (const float*)d_in[3];
    const float* whh0   = (const float*)d_in[4];
    const float* bih0   = (const float*)d_in[5];
    const float* bhh0   = (const float*)d_in[6];
    const float* wih1   = (const float*)d_in[7];
    const float* whh1   = (const float*)d_in[8];
    const float* bih1   = (const float*)d_in[9];
    const float* bhh1   = (const float*)d_in[10];
    const float* wih2   = (const float*)d_in[11];
    const float* whh2   = (const float*)d_in[12];
    const float* bih2   = (const float*)d_in[13];
    const float* bhh2   = (const float*)d_in[14];
    const float* w_out  = (const float*)d_in[15];
    const float* b_out  = (const float*)d_in[16];
    unsigned short* wpd = (unsigned short*)d_ws;   // 552,960 B used
    float* out          = (float*)d_out;

    prep_kernel<<<(WP_TOTAL + 255) / 256, 256, 0, stream>>>(
        w_proj, wih0, bih0, whh0, bhh0, wih1, bih1, whh1, bhh1,
        wih2, bih2, whh2, bhh2, w_out, b_out, wpd);

    rnn_kernel<<<NBLK, NTHR, 0, stream>>>(enc, b_proj, wpd, out);
}